// Round 1
// baseline (178579.663 us; speedup 1.0000x reference)
//
#include <hip/hip_runtime.h>

#define T_STEPS 100000
#define NWG 32
#define TPB 512        // 8 waves
#define HD 512
#define ID 128
#define UPW 16         // hidden units per workgroup
#define ROWS 64        // gate rows per workgroup = 4*UPW

// Persistent LSTM kernel. Weights stay in VGPRs; per-step cross-workgroup
// h all-gather uses 64-bit {tag,value} agent-scope atomics, double-buffered.
__global__ __launch_bounds__(TPB, 2) void lstm_persist(
    const float* __restrict__ x,      // [T,128]
    const float* __restrict__ W_ih,   // [2048,128]
    const float* __restrict__ b_ih,   // [2048]
    const float* __restrict__ W_hh,   // [2048,512]
    const float* __restrict__ b_hh,   // [2048]
    const float* __restrict__ W_out,  // [512]
    const float* __restrict__ b_out,  // [1]
    float* __restrict__ out,          // [T]
    unsigned long long* __restrict__ hpk) // [2][512] packed {tag,val}
{
  const int w    = blockIdx.x;   // 0..31
  const int tid  = threadIdx.x;  // 0..511
  const int wave = tid >> 6;     // 0..7
  const int lane = tid & 63;
  const int qr   = tid >> 3;     // reduction row 0..63
  const int c8   = tid & 7;      // reduction chunk 0..7

  __shared__ float h_lds[HD];
  __shared__ float part_lds[ROWS][65];  // +1 pad: conflict-free transpose reduce
  __shared__ float gates_lds[ROWS];
  __shared__ float xp_lds[2][ROWS];
  __shared__ float bsum_lds[ROWS];

  // local gate-row q (0..63) -> global row: gate=(q>>4), unit=16*w+(q&15)
  // ---- stage weights into registers (one-time) ----
  float Whh[8][8];  // wave owns rows q=wave*8+p; lane covers k = lane+64*j
  #pragma unroll
  for (int p = 0; p < 8; ++p) {
    const int q = wave*8 + p;
    const int R = (q>>4)*HD + UPW*w + (q&15);
    const float* src = W_hh + (size_t)R*HD + lane;
    #pragma unroll
    for (int j = 0; j < 8; ++j) Whh[p][j] = src[64*j];
  }
  float Wih[16];    // thread (qr,c8) owns row qr, k in [c8*16, c8*16+16)
  {
    const int R = (qr>>4)*HD + UPW*w + (qr&15);
    const float* src = W_ih + (size_t)R*ID + c8*16;
    #pragma unroll
    for (int i = 0; i < 16; ++i) Wih[i] = src[i];
  }
  float Wo[8];
  if (wave == 0) {
    #pragma unroll
    for (int j = 0; j < 8; ++j) Wo[j] = W_out[lane + 64*j];
  }
  const float bo = b_out[0];

  if (tid < ROWS) {
    const int R = (tid>>4)*HD + UPW*w + (tid&15);
    bsum_lds[tid] = b_ih[R] + b_hh[R];
  }
  __syncthreads();

  // publish h0 = 0 with tag 0 into slot 0 (own slice only)
  if (tid < UPW) {
    __hip_atomic_store(&hpk[UPW*w + tid], 0ull,
                       __ATOMIC_RELAXED, __HIP_MEMORY_SCOPE_AGENT);
  }

  // input projection for x row 0 (consumed at iter t=1)
  {
    float s = 0.f;
    const float* xr = x + c8*16;
    #pragma unroll
    for (int i = 0; i < 16; ++i) s += Wih[i]*xr[i];
    s += __shfl_xor(s, 1); s += __shfl_xor(s, 2); s += __shfl_xor(s, 4);
    if (c8 == 0) xp_lds[0][qr] = s + bsum_lds[qr];
  }

  float creg = 0.f;  // cell state for unit (16*w + tid), tid<16

  for (int t = 1; t <= T_STEPS; ++t) {
    const unsigned int tag = (unsigned int)(t - 1);
    unsigned long long* sl = hpk + (size_t)((t - 1) & 1) * HD;

    // ---- poll + gather h_{t-1}: one element per thread ----
    unsigned long long v;
    unsigned int guard = 0;
    do {
      v = __hip_atomic_load(&sl[tid], __ATOMIC_RELAXED, __HIP_MEMORY_SCOPE_AGENT);
    } while ((unsigned int)(v >> 32) != tag && ++guard < (1u << 27));
    h_lds[tid] = __uint_as_float((unsigned int)v);
    __syncthreads();   // sync1: h ready

    // ---- output p_{t-1} = sigmoid(W_out . h_{t-1} + b) -> out[t-2] ----
    // round-robin across wgs (every wg has full h anyway)
    if (wave == 0 && t >= 2 && ((t - 2) & 31) == w) {
      float s = 0.f;
      #pragma unroll
      for (int j = 0; j < 8; ++j) s = fmaf(Wo[j], h_lds[lane + 64*j], s);
      s += __shfl_xor(s, 1);  s += __shfl_xor(s, 2);  s += __shfl_xor(s, 4);
      s += __shfl_xor(s, 8);  s += __shfl_xor(s, 16); s += __shfl_xor(s, 32);
      if (lane == 0) out[t - 2] = 1.f / (1.f + __expf(-(s + bo)));
    }

    // ---- matvec partials: 64 FMAs/lane from registers ----
    float hreg[8];
    #pragma unroll
    for (int j = 0; j < 8; ++j) hreg[j] = h_lds[lane + 64*j];
    #pragma unroll
    for (int p = 0; p < 8; ++p) {
      float s = 0.f;
      #pragma unroll
      for (int j = 0; j < 8; ++j) s = fmaf(Whh[p][j], hreg[j], s);
      part_lds[wave*8 + p][lane] = s;
    }
    __syncthreads();   // sync2: partials ready

    // ---- reduce 64 lane-partials per row -> gates ----
    {
      float s = 0.f;
      #pragma unroll
      for (int i = 0; i < 8; ++i) s += part_lds[qr][c8*8 + i];
      s += __shfl_xor(s, 1); s += __shfl_xor(s, 2); s += __shfl_xor(s, 4);
      if (c8 == 0) gates_lds[qr] = s + xp_lds[(t - 1) & 1][qr];
    }
    __syncthreads();   // sync3: gates ready

    // ---- activations, cell update, publish h_t (16 threads) ----
    if (tid < UPW) {
      const float ii = 1.f / (1.f + __expf(-gates_lds[tid]));
      const float ff = 1.f / (1.f + __expf(-gates_lds[16 + tid]));
      const float e2g = __expf(2.f * gates_lds[32 + tid]);
      const float gg = 1.f - 2.f / (e2g + 1.f);
      const float oo = 1.f / (1.f + __expf(-gates_lds[48 + tid]));
      creg = ff * creg + ii * gg;
      const float e2c = __expf(2.f * creg);
      const float hh = oo * (1.f - 2.f / (e2c + 1.f));
      const unsigned long long pk =
          ((unsigned long long)(unsigned int)t << 32) |
          (unsigned long long)__float_as_uint(hh);
      __hip_atomic_store(&hpk[(size_t)(t & 1) * HD + UPW*w + tid], pk,
                         __ATOMIC_RELAXED, __HIP_MEMORY_SCOPE_AGENT);
    }

    // ---- input projection for x row t (consumed next iter); off critical path
    if (t < T_STEPS) {
      float s = 0.f;
      const float* xr = x + (size_t)t * ID + c8*16;
      #pragma unroll
      for (int i = 0; i < 16; ++i) s += Wih[i]*xr[i];
      s += __shfl_xor(s, 1); s += __shfl_xor(s, 2); s += __shfl_xor(s, 4);
      if (c8 == 0) xp_lds[t & 1][qr] = s + bsum_lds[qr];
    }
  }

  // ---- tail: out[T-1] = sigmoid(W_out . h_T + b), done by wg 0 ----
  if (w == 0) {
    unsigned long long* sl = hpk + (size_t)(T_STEPS & 1) * HD;
    unsigned long long v;
    unsigned int guard = 0;
    do {
      v = __hip_atomic_load(&sl[tid], __ATOMIC_RELAXED, __HIP_MEMORY_SCOPE_AGENT);
    } while ((unsigned int)(v >> 32) != (unsigned int)T_STEPS && ++guard < (1u << 27));
    h_lds[tid] = __uint_as_float((unsigned int)v);
    __syncthreads();
    if (wave == 0) {
      float s = 0.f;
      #pragma unroll
      for (int j = 0; j < 8; ++j) s = fmaf(Wo[j], h_lds[lane + 64*j], s);
      s += __shfl_xor(s, 1);  s += __shfl_xor(s, 2);  s += __shfl_xor(s, 4);
      s += __shfl_xor(s, 8);  s += __shfl_xor(s, 16); s += __shfl_xor(s, 32);
      if (lane == 0) out[T_STEPS - 1] = 1.f / (1.f + __expf(-(s + bo)));
    }
  }
}

extern "C" void kernel_launch(void* const* d_in, const int* in_sizes, int n_in,
                              void* d_out, int out_size, void* d_ws, size_t ws_size,
                              hipStream_t stream) {
  (void)in_sizes; (void)n_in; (void)out_size; (void)ws_size;
  const float* x     = (const float*)d_in[0];
  const float* W_ih  = (const float*)d_in[1];
  const float* b_ih  = (const float*)d_in[2];
  const float* W_hh  = (const float*)d_in[3];
  const float* b_hh  = (const float*)d_in[4];
  const float* W_out = (const float*)d_in[5];
  const float* b_out = (const float*)d_in[6];
  float* out = (float*)d_out;
  unsigned long long* hpk = (unsigned long long*)d_ws;  // 2*512*8 = 8 KB

  lstm_persist<<<NWG, TPB, 0, stream>>>(x, W_ih, b_ih, W_hh, b_hh,
                                        W_out, b_out, out, hpk);
}